// Round 7
// baseline (153.930 us; speedup 1.0000x reference)
//
#include <hip/hip_runtime.h>
#include <math.h>

typedef __attribute__((ext_vector_type(8))) short bf16x8;
typedef __attribute__((ext_vector_type(4))) float f32x4;

// ================= compile-time Clebsch-Gordan tables =================
constexpr double cfact(int n){ double r=1.0; for(int i=2;i<=n;++i) r*=(double)i; return r; }
constexpr double csqrt_(double x){ double g=(x>1.0)?x:1.0; for(int i=0;i<100;++i) g=0.5*(g+x/g); return g; }
constexpr double cg_coef_(int l1,int m1,int l2,int m2,int l,int m){
  double pre = csqrt_((double)(2*l+1)*cfact(l1+l2-l)*cfact(l1-l2+l)*cfact(-l1+l2+l)/cfact(l1+l2+l+1));
  pre = pre*csqrt_(cfact(l+m)*cfact(l-m)*cfact(l1-m1)*cfact(l1+m1)*cfact(l2-m2)*cfact(l2+m2));
  double s=0.0;
  for(int k=0;k<=l1+l2-l;++k){
    int d0=k,d1=l1+l2-l-k,d2=l1-m1-k,d3=l2+m2-k,d4=l-l2+m1+k,d5=l-l1-m2+k;
    if(d0<0||d1<0||d2<0||d3<0||d4<0||d5<0) continue;
    double den=cfact(d0)*cfact(d1)*cfact(d2)*cfact(d3)*cfact(d4)*cfact(d5);
    s+=((k&1)?-1.0:1.0)/den;
  }
  return pre*s;
}
struct CGList{ int n; float coef[64]; int mi[64]; int ni[64]; int pi[64]; };
constexpr CGList build_cg(int l1,int l2,int l){
  CGList T{};
  for(int i=0;i<2*l1+1;++i){
    for(int j=0;j<2*l2+1;++j){
      int m1=i-l1, m2=j-l2, m=m1+m2;
      if(m<-l||m>l) continue;
      double c=cg_coef_(l1,m1,l2,m2,l,m);
      if(c>1e-12||c<-1e-12){
        T.coef[T.n]=(float)c; T.mi[T.n]=i; T.ni[T.n]=j; T.pi[T.n]=m+l; T.n++;
      }
    }
  }
  return T;
}

// ================= layout constants =================
__device__ __host__ constexpr int AOFF(int l){ return l==0?0: l==1?16: l==2?64:144; }
__device__ __host__ constexpr int MLs(int l){ return l==0?1024: l==1?1536: l==2?1792:1536; }
__device__ __host__ constexpr int WOFF(int l){ return l==0?0: l==1?16384: l==2?40960:69632; }
__device__ __host__ constexpr int SOFF(int l){ return l==0?0: l==1?1024: l==2?2560:4352; }
__device__ __host__ constexpr int ABASE(int l){ return l==0?0: l==1?65536: l==2?163840:278528; }

#define DEVFN __device__ __forceinline__
#define BP 68    // btile row pitch in words
#define AP 68    // ldsA row pitch in words

DEVFN unsigned f2bf2(float x, float y){
  unsigned ux = __float_as_uint(x); ux = (ux + 0x7FFFu + ((ux>>16)&1u)) >> 16;
  unsigned uy = __float_as_uint(y); uy = (uy + 0x7FFFu + ((uy>>16)&1u)) >> 16;
  return (ux & 0xFFFFu) | (uy << 16);
}

template<int L1,int L2,int L>
DEVFN void cg_accum(const float2* F1, const float2* F2, float2* mid){
  constexpr CGList T = build_cg(L1,L2,L);
  #pragma unroll
  for(int e=0;e<T.n;++e){
    const float c = T.coef[e];
    const float2 a = F1[T.mi[e]];
    const float2 b = F2[T.ni[e]];
    float pr = a.x*b.x - a.y*b.y;
    float pim= a.x*b.y + a.y*b.x;
    mid[T.pi[e]].x += c*pr;
    mid[T.pi[e]].y += c*pim;
  }
}

// ===== K1: sumsq partials, GLOBAL-direct (no LDS, no barriers) + W-convert =====
template<int L1,int L2,int L>
DEVFN void k1g(const float2* __restrict__ act2, int b0, int u, int bh,
               float& ssa, float& ssb){
  constexpr int N1=2*L1+1, N2=2*L2+1, NP=2*L+1;
  const int t = u>>3, s0 = (u&7)*2;
  const float2* base1  = act2 + AOFF(L1) + t*N1;
  const float2* base2a = act2 + AOFF(L2) + s0*N2;
  const float2* base2b = base2a + N2;
  #pragma unroll 2
  for(int bi=0;bi<16;++bi){
    const size_t ro = (size_t)(b0 + bh*16 + bi)*256;
    float2 F1[N1], F2a[N2], F2b[N2], mida[NP], midb[NP];
    #pragma unroll
    for(int m=0;m<N1;++m) F1[m]=base1[ro+m];
    #pragma unroll
    for(int n=0;n<N2;++n){ F2a[n]=base2a[ro+n]; F2b[n]=base2b[ro+n]; }
    #pragma unroll
    for(int p=0;p<NP;++p){ mida[p]=make_float2(0.f,0.f); midb[p]=make_float2(0.f,0.f); }
    cg_accum<L1,L2,L>(F1,F2a,mida);
    cg_accum<L1,L2,L>(F1,F2b,midb);
    #pragma unroll
    for(int p=0;p<NP;++p){
      ssa += mida[p].x*mida[p].x + mida[p].y*mida[p].y;
      ssb += midb[p].x*midb[p].x + midb[p].y*midb[p].y;
    }
  }
}

DEVFN void convW(const float* __restrict__ W, short* __restrict__ A, int idx){
  int l = (idx<1024)?0 : (idx<2560)?1 : (idx<4352)?2 : 3;
  int c = idx - SOFF(l);
  int Ml = MLs(l);
  const float2* wbase = (const float2*)W + WOFF(l) + c;
  unsigned* Aw = (unsigned*)(A + ABASE(l));   // row pitch = Ml words
  #pragma unroll 4
  for(int o=0;o<16;++o){
    float2 w = wbase[(size_t)o*Ml];
    Aw[(size_t)o*Ml + c]      = f2bf2(w.x, -w.y);
    Aw[(size_t)(o+16)*Ml + c] = f2bf2(w.y,  w.x);
  }
}

__global__ __launch_bounds__(256) void k_sumsq(const float* __restrict__ act,
                                               float2* __restrict__ part,
                                               const float* __restrict__ W,
                                               short* __restrict__ A){
  const int bid = blockIdx.x;                // 1472 sumsq + 23 W-convert
  const int tid = threadIdx.x;
  if(bid >= 1472){                           // W -> bf16 A (no scale), hidden
    convW(W, A, (bid-1472)*256 + tid);
    return;
  }
  const int order[23] = {22,16,21,18,15,20,13,9,14,8,17,7,12,6,10,3,5,19,2,11,1,4,0};
  const int ti = order[bid>>6];
  const int chunk = bid&63;
  const int b0 = chunk*32;
  const int u = tid & 127, bh = tid >> 7;    // channels (2u,2u+1), batch half
  const float2* act2 = (const float2*)act;
  float ssa=0.f, ssb=0.f;
  switch(ti){
    case 0:  k1g<0,0,0>(act2,b0,u,bh,ssa,ssb); break;
    case 1:  k1g<1,1,0>(act2,b0,u,bh,ssa,ssb); break;
    case 2:  k1g<2,2,0>(act2,b0,u,bh,ssa,ssb); break;
    case 3:  k1g<3,3,0>(act2,b0,u,bh,ssa,ssb); break;
    case 4:  k1g<1,0,1>(act2,b0,u,bh,ssa,ssb); break;
    case 5:  k1g<1,1,1>(act2,b0,u,bh,ssa,ssb); break;
    case 6:  k1g<2,1,1>(act2,b0,u,bh,ssa,ssb); break;
    case 7:  k1g<2,2,1>(act2,b0,u,bh,ssa,ssb); break;
    case 8:  k1g<3,2,1>(act2,b0,u,bh,ssa,ssb); break;
    case 9:  k1g<3,3,1>(act2,b0,u,bh,ssa,ssb); break;
    case 10: k1g<1,1,2>(act2,b0,u,bh,ssa,ssb); break;
    case 11: k1g<2,0,2>(act2,b0,u,bh,ssa,ssb); break;
    case 12: k1g<2,1,2>(act2,b0,u,bh,ssa,ssb); break;
    case 13: k1g<2,2,2>(act2,b0,u,bh,ssa,ssb); break;
    case 14: k1g<3,1,2>(act2,b0,u,bh,ssa,ssb); break;
    case 15: k1g<3,2,2>(act2,b0,u,bh,ssa,ssb); break;
    case 16: k1g<3,3,2>(act2,b0,u,bh,ssa,ssb); break;
    case 17: k1g<2,1,3>(act2,b0,u,bh,ssa,ssb); break;
    case 18: k1g<2,2,3>(act2,b0,u,bh,ssa,ssb); break;
    case 19: k1g<3,0,3>(act2,b0,u,bh,ssa,ssb); break;
    case 20: k1g<3,1,3>(act2,b0,u,bh,ssa,ssb); break;
    case 21: k1g<3,2,3>(act2,b0,u,bh,ssa,ssb); break;
    default: k1g<3,3,3>(act2,b0,u,bh,ssa,ssb); break;
  }
  // coalesced partial store: row = ti*128 + chunk*2 + bh
  part[(size_t)((ti*64 + chunk)*2 + bh)*128 + u] = make_float2(ssa, ssb);
}

// ==== K2: tiny — reduce 128 partial rows per triple -> scale table s[5888] ====
__global__ __launch_bounds__(256) void k_scale(const float* __restrict__ bn,
                                               const float2* __restrict__ part,
                                               float* __restrict__ s){
  const int ti = blockIdx.x;                 // 23
  const int ch = threadIdx.x;                // 256 channels
  const int idx = ti*256 + ch;
  const int u = ch>>1;
  const float2* ps = part + (size_t)ti*128*128 + u;
  float sum = 0.f;
  #pragma unroll 8
  for(int r=0;r<128;++r){
    float2 v = ps[(size_t)r*128];
    sum += (ch&1) ? v.y : v.x;
  }
  int l = (idx<1024)?0 : (idx<2560)?1 : (idx<4352)?2 : 3;
  float divi = (l==0)?(1.f/2048.f) : (l==1)?(1.f/6144.f) : (l==2)?(1.f/10240.f) : (1.f/14336.f);
  float bstd = sqrtf(sum*divi);
  float nstd = 0.5f*(bn[idx]+bstd);
  s[idx] = 1.f/(nstd+1e-5f);
}

// ======== K3: fused recompute-GEMM (global-direct phase1, lean LDS) ========
// Block = 8 batches of one l. Per 64-word chunk:
//   { phase1 CG recompute (x s[ch]) -> btile, act read DIRECT from global
//     (block's 8 rows = 16 KB, L1/L2-hot);
//     land A chunk cc (loads issued LAST iteration -> latency hidden under
//     phase1's VALU) -> single ldsA buffer (safe: previous MFMA read ended
//     at the last barrier, which precedes this write in program order);
//     issue A loads for chunk cc+1; barrier;
//     MFMA (A from ldsA, B from btile); barrier }
// Full-K register accumulation -> single float2 store per output element.
// LDS = 17408 (btile) + 8704 (ldsA) = 26112 B; occupancy VGPR-capped at
// 4 blocks/CU (16 waves).

#define BT_B   0
#define LA_B   17408

template<int NTIL>
DEVFN void kf_pre(char* smem){
  const int tid = threadIdx.x;
  unsigned* btile = (unsigned*)(smem + BT_B);
  for(int i=tid; i<NTIL*16*BP; i+=256) btile[i]=0;
  __syncthreads();
}

template<int L1,int L2,int L,int Q,int NTIL>
DEVFN void kf_triple(const float2* __restrict__ act2, int b0, char* smem,
                     const unsigned* __restrict__ Aw,
                     const float* __restrict__ sg, f32x4& cR, f32x4& cI){
  constexpr int N1=2*L1+1, N2=2*L2+1, NP=2*L+1;
  constexpr int Ml = MLs(L);
  unsigned* btile  = (unsigned*)(smem + BT_B);
  unsigned* ldsA   = (unsigned*)(smem + LA_B);
  const int tid = threadIdx.x;
  const int lane = tid & 63, w = tid >> 6;
  const int col = lane & 15, quad = lane >> 4;
  const int up = tid & 31, bi = tid >> 5;    // channel-pair-in-chunk, batch
  const int r0 = tid>>4,       j0 = (tid&15)*4;
  const int r1 = (tid+256)>>4;
  const float2* arow = act2 + (size_t)(b0+bi)*256;
  // issue chunk-0 A loads (land after phase1 of cc=0)
  uint4 v0 = *(const uint4*)(Aw + (size_t)r0*Ml + Q*256 + j0);
  uint4 v1 = *(const uint4*)(Aw + (size_t)r1*Ml + Q*256 + j0);
  #pragma unroll 1
  for(int cc=0; cc<4; ++cc){
    // ---- phase1: CG recompute (scaled) for 64 K-words x 8 batches ----
    {
      const float2 s2 = *(const float2*)(sg + SOFF(L) + Q*256 + cc*64 + 2*up);
      const int u = cc*32 + up;              // channel pair (2u,2u+1)
      const int t = u>>3, s0 = (u&7)*2;
      float2 F1[N1], F2a[N2], F2b[N2], mida[NP], midb[NP];
      #pragma unroll
      for(int m=0;m<N1;++m) F1[m]=arow[AOFF(L1)+t*N1+m];
      #pragma unroll
      for(int n=0;n<N2;++n){
        F2a[n]=arow[AOFF(L2)+s0*N2+n];
        F2b[n]=arow[AOFF(L2)+(s0+1)*N2+n];
      }
      #pragma unroll
      for(int p=0;p<NP;++p){ mida[p]=make_float2(0.f,0.f); midb[p]=make_float2(0.f,0.f); }
      cg_accum<L1,L2,L>(F1,F2a,mida);
      cg_accum<L1,L2,L>(F1,F2b,midb);
      #pragma unroll
      for(int p=0;p<NP;++p){
        uint2 v;
        v.x = f2bf2(mida[p].x*s2.x, mida[p].y*s2.x);
        v.y = f2bf2(midb[p].x*s2.y, midb[p].y*s2.y);
        *(uint2*)(btile + (size_t)(bi*NP+p)*BP + 2*up) = v;
      }
    }
    // ---- land A chunk cc (loads issued last iteration / prologue) ----
    *(uint4*)(ldsA + r0*AP + j0) = v0;
    *(uint4*)(ldsA + r1*AP + j0) = v1;
    // ---- issue A loads for chunk cc+1 (hidden under next phase1) ----
    if(cc<3){
      const int base = Q*256 + (cc+1)*64;
      v0 = *(const uint4*)(Aw + (size_t)r0*Ml + base + j0);
      v1 = *(const uint4*)(Aw + (size_t)r1*Ml + base + j0);
    }
    __syncthreads();
    // ---- MFMA accumulate (A and B both from LDS) ----
    if(w < NTIL){
      const unsigned* ar0 = ldsA + col*AP + quad*4;
      const unsigned* ar1 = ldsA + (col+16)*AP + quad*4;
      const unsigned* bb  = btile + (w*16+col)*BP + quad*4;
      #pragma unroll
      for(int ks=0; ks<4; ++ks){
        bf16x8 b  = *(const bf16x8*)(bb + ks*16);
        bf16x8 A0 = *(const bf16x8*)(ar0 + ks*16);
        bf16x8 A1 = *(const bf16x8*)(ar1 + ks*16);
        cR = __builtin_amdgcn_mfma_f32_16x16x32_bf16(A0, b, cR, 0, 0, 0);
        cI = __builtin_amdgcn_mfma_f32_16x16x32_bf16(A1, b, cI, 0, 0, 0);
      }
    }
    __syncthreads();
  }
}

template<int L,int NTIL>
DEVFN void kf_epi(float* __restrict__ out, int b0, f32x4 cR, f32x4 cI){
  constexpr int NP = 2*L+1;
  const int tid = threadIdx.x, lane = tid & 63, w = tid >> 6;
  const int col = lane & 15, quad = lane >> 4;
  if(w < NTIL){
    const int r = w*16 + col;
    if(r < 8*NP){
      const int b = b0 + r/NP, p = r - (r/NP)*NP;
      float2* o2 = (float2*)out + (size_t)b*256 + AOFF(L);
      #pragma unroll
      for(int i=0;i<4;++i) o2[(quad*4+i)*NP + p] = make_float2(cR[i], cI[i]);
    }
  }
}

__global__ __launch_bounds__(256,4) void k_fusedall(const float* __restrict__ act,
    const short* __restrict__ A, const float* __restrict__ sg,
    float* __restrict__ out){
  __shared__ __align__(16) char smem[26112];
  const int bid = blockIdx.x;                             // 1024
  const float2* act2 = (const float2*)act;
  f32x4 cR={0.f,0.f,0.f,0.f}, cI={0.f,0.f,0.f,0.f};
  if(bid < 256){                                          // l=3, rows 56, NTIL 4
    const int b0 = bid*8;
    kf_pre<4>(smem);
    const unsigned* Aw=(const unsigned*)(A+ABASE(3));
    kf_triple<2,1,3,0,4>(act2,b0,smem,Aw,sg,cR,cI);
    kf_triple<2,2,3,1,4>(act2,b0,smem,Aw,sg,cR,cI);
    kf_triple<3,0,3,2,4>(act2,b0,smem,Aw,sg,cR,cI);
    kf_triple<3,1,3,3,4>(act2,b0,smem,Aw,sg,cR,cI);
    kf_triple<3,2,3,4,4>(act2,b0,smem,Aw,sg,cR,cI);
    kf_triple<3,3,3,5,4>(act2,b0,smem,Aw,sg,cR,cI);
    kf_epi<3,4>(out,b0,cR,cI);
  } else if(bid < 512){                                   // l=2, rows 40, NTIL 3
    const int b0 = (bid-256)*8;
    kf_pre<3>(smem);
    const unsigned* Aw=(const unsigned*)(A+ABASE(2));
    kf_triple<1,1,2,0,3>(act2,b0,smem,Aw,sg,cR,cI);
    kf_triple<2,0,2,1,3>(act2,b0,smem,Aw,sg,cR,cI);
    kf_triple<2,1,2,2,3>(act2,b0,smem,Aw,sg,cR,cI);
    kf_triple<2,2,2,3,3>(act2,b0,smem,Aw,sg,cR,cI);
    kf_triple<3,1,2,4,3>(act2,b0,smem,Aw,sg,cR,cI);
    kf_triple<3,2,2,5,3>(act2,b0,smem,Aw,sg,cR,cI);
    kf_triple<3,3,2,6,3>(act2,b0,smem,Aw,sg,cR,cI);
    kf_epi<2,3>(out,b0,cR,cI);
  } else if(bid < 768){                                   // l=1, rows 24, NTIL 2
    const int b0 = (bid-512)*8;
    kf_pre<2>(smem);
    const unsigned* Aw=(const unsigned*)(A+ABASE(1));
    kf_triple<1,0,1,0,2>(act2,b0,smem,Aw,sg,cR,cI);
    kf_triple<1,1,1,1,2>(act2,b0,smem,Aw,sg,cR,cI);
    kf_triple<2,1,1,2,2>(act2,b0,smem,Aw,sg,cR,cI);
    kf_triple<2,2,1,3,2>(act2,b0,smem,Aw,sg,cR,cI);
    kf_triple<3,2,1,4,2>(act2,b0,smem,Aw,sg,cR,cI);
    kf_triple<3,3,1,5,2>(act2,b0,smem,Aw,sg,cR,cI);
    kf_epi<1,2>(out,b0,cR,cI);
  } else {                                                // l=0, rows 8, NTIL 1
    const int b0 = (bid-768)*8;
    kf_pre<1>(smem);
    const unsigned* Aw=(const unsigned*)(A+ABASE(0));
    kf_triple<0,0,0,0,1>(act2,b0,smem,Aw,sg,cR,cI);
    kf_triple<1,1,0,1,1>(act2,b0,smem,Aw,sg,cR,cI);
    kf_triple<2,2,0,2,1>(act2,b0,smem,Aw,sg,cR,cI);
    kf_triple<3,3,0,3,1>(act2,b0,smem,Aw,sg,cR,cI);
    kf_epi<0,1>(out,b0,cR,cI);
  }
}

// ================= host launch =================
extern "C" void kernel_launch(void* const* d_in, const int* in_sizes, int n_in,
                              void* d_out, int out_size, void* d_ws, size_t ws_size,
                              hipStream_t stream) {
  const float* act = (const float*)d_in[0];   // (2048,256,2) f32
  const float* W   = (const float*)d_in[1];   // (94208,2) f32
  const float* bn  = (const float*)d_in[2];   // (5888,) f32
  float* out = (float*)d_out;                 // (2048,256,2) f32

  float*  s    = (float*)d_ws;                            // 5888 f32 scale table
  short*  A    = (short*)((char*)d_ws + 24576);           // 754 KB bf16 A (unscaled)
  float2* part = (float2*)((char*)d_ws + 1048576);        // 3 MB partials

  hipLaunchKernelGGL(k_sumsq,   dim3(1495), dim3(256), 0, stream, act, part, W, A);
  hipLaunchKernelGGL(k_scale,   dim3(23),   dim3(256), 0, stream, bn, part, s);
  hipLaunchKernelGGL(k_fusedall,dim3(1024), dim3(256), 0, stream, act, A, s, out);
}

// Round 8
// 142.765 us; speedup vs baseline: 1.0782x; 1.0782x over previous
//
#include <hip/hip_runtime.h>
#include <math.h>

typedef __attribute__((ext_vector_type(8))) short bf16x8;
typedef __attribute__((ext_vector_type(4))) float f32x4;

// ================= compile-time Clebsch-Gordan tables =================
constexpr double cfact(int n){ double r=1.0; for(int i=2;i<=n;++i) r*=(double)i; return r; }
constexpr double csqrt_(double x){ double g=(x>1.0)?x:1.0; for(int i=0;i<100;++i) g=0.5*(g+x/g); return g; }
constexpr double cg_coef_(int l1,int m1,int l2,int m2,int l,int m){
  double pre = csqrt_((double)(2*l+1)*cfact(l1+l2-l)*cfact(l1-l2+l)*cfact(-l1+l2+l)/cfact(l1+l2+l+1));
  pre = pre*csqrt_(cfact(l+m)*cfact(l-m)*cfact(l1-m1)*cfact(l1+m1)*cfact(l2-m2)*cfact(l2+m2));
  double s=0.0;
  for(int k=0;k<=l1+l2-l;++k){
    int d0=k,d1=l1+l2-l-k,d2=l1-m1-k,d3=l2+m2-k,d4=l-l2+m1+k,d5=l-l1-m2+k;
    if(d0<0||d1<0||d2<0||d3<0||d4<0||d5<0) continue;
    double den=cfact(d0)*cfact(d1)*cfact(d2)*cfact(d3)*cfact(d4)*cfact(d5);
    s+=((k&1)?-1.0:1.0)/den;
  }
  return pre*s;
}
struct CGList{ int n; float coef[64]; int mi[64]; int ni[64]; int pi[64]; };
constexpr CGList build_cg(int l1,int l2,int l){
  CGList T{};
  for(int i=0;i<2*l1+1;++i){
    for(int j=0;j<2*l2+1;++j){
      int m1=i-l1, m2=j-l2, m=m1+m2;
      if(m<-l||m>l) continue;
      double c=cg_coef_(l1,m1,l2,m2,l,m);
      if(c>1e-12||c<-1e-12){
        T.coef[T.n]=(float)c; T.mi[T.n]=i; T.ni[T.n]=j; T.pi[T.n]=m+l; T.n++;
      }
    }
  }
  return T;
}

// ================= layout constants =================
__device__ __host__ constexpr int AOFF(int l){ return l==0?0: l==1?16: l==2?64:144; }
__device__ __host__ constexpr int MLs(int l){ return l==0?1024: l==1?1536: l==2?1792:1536; }
__device__ __host__ constexpr int WOFF(int l){ return l==0?0: l==1?16384: l==2?40960:69632; }
__device__ __host__ constexpr int SOFF(int l){ return l==0?0: l==1?1024: l==2?2560:4352; }
__device__ __host__ constexpr int ABASE(int l){ return l==0?0: l==1?65536: l==2?163840:278528; }

#define DEVFN __device__ __forceinline__
#define BP 68    // btile row pitch in words
#define AP 68    // ldsA row pitch in words

DEVFN unsigned f2bf2(float x, float y){
  unsigned ux = __float_as_uint(x); ux = (ux + 0x7FFFu + ((ux>>16)&1u)) >> 16;
  unsigned uy = __float_as_uint(y); uy = (uy + 0x7FFFu + ((uy>>16)&1u)) >> 16;
  return (ux & 0xFFFFu) | (uy << 16);
}

template<int L1,int L2,int L>
DEVFN void cg_accum(const float2* F1, const float2* F2, float2* mid){
  constexpr CGList T = build_cg(L1,L2,L);
  #pragma unroll
  for(int e=0;e<T.n;++e){
    const float c = T.coef[e];
    const float2 a = F1[T.mi[e]];
    const float2 b = F2[T.ni[e]];
    float pr = a.x*b.x - a.y*b.y;
    float pim= a.x*b.y + a.y*b.x;
    mid[T.pi[e]].x += c*pr;
    mid[T.pi[e]].y += c*pim;
  }
}

// ===== K1: sumsq partials, GLOBAL-direct (no LDS, no barriers) + W-convert =====
template<int L1,int L2,int L>
DEVFN void k1g(const float2* __restrict__ act2, int b0, int u, int bh,
               float& ssa, float& ssb){
  constexpr int N1=2*L1+1, N2=2*L2+1, NP=2*L+1;
  const int t = u>>3, s0 = (u&7)*2;
  const float2* base1  = act2 + AOFF(L1) + t*N1;
  const float2* base2a = act2 + AOFF(L2) + s0*N2;
  const float2* base2b = base2a + N2;
  #pragma unroll 2
  for(int bi=0;bi<16;++bi){
    const size_t ro = (size_t)(b0 + bh*16 + bi)*256;
    float2 F1[N1], F2a[N2], F2b[N2], mida[NP], midb[NP];
    #pragma unroll
    for(int m=0;m<N1;++m) F1[m]=base1[ro+m];
    #pragma unroll
    for(int n=0;n<N2;++n){ F2a[n]=base2a[ro+n]; F2b[n]=base2b[ro+n]; }
    #pragma unroll
    for(int p=0;p<NP;++p){ mida[p]=make_float2(0.f,0.f); midb[p]=make_float2(0.f,0.f); }
    cg_accum<L1,L2,L>(F1,F2a,mida);
    cg_accum<L1,L2,L>(F1,F2b,midb);
    #pragma unroll
    for(int p=0;p<NP;++p){
      ssa += mida[p].x*mida[p].x + mida[p].y*mida[p].y;
      ssb += midb[p].x*midb[p].x + midb[p].y*midb[p].y;
    }
  }
}

DEVFN void convW(const float* __restrict__ W, short* __restrict__ A, int idx){
  int l = (idx<1024)?0 : (idx<2560)?1 : (idx<4352)?2 : 3;
  int c = idx - SOFF(l);
  int Ml = MLs(l);
  const float2* wbase = (const float2*)W + WOFF(l) + c;
  unsigned* Aw = (unsigned*)(A + ABASE(l));   // row pitch = Ml words
  #pragma unroll 4
  for(int o=0;o<16;++o){
    float2 w = wbase[(size_t)o*Ml];
    Aw[(size_t)o*Ml + c]      = f2bf2(w.x, -w.y);
    Aw[(size_t)(o+16)*Ml + c] = f2bf2(w.y,  w.x);
  }
}

__global__ __launch_bounds__(256) void k_sumsq(const float* __restrict__ act,
                                               float2* __restrict__ part,
                                               const float* __restrict__ W,
                                               short* __restrict__ A){
  const int bid = blockIdx.x;                // 1472 sumsq + 23 W-convert
  const int tid = threadIdx.x;
  if(bid >= 1472){                           // W -> bf16 A (no scale), hidden
    convW(W, A, (bid-1472)*256 + tid);
    return;
  }
  const int order[23] = {22,16,21,18,15,20,13,9,14,8,17,7,12,6,10,3,5,19,2,11,1,4,0};
  const int ti = order[bid>>6];
  const int chunk = bid&63;
  const int b0 = chunk*32;
  const int u = tid & 127, bh = tid >> 7;    // channels (2u,2u+1), batch half
  const float2* act2 = (const float2*)act;
  float ssa=0.f, ssb=0.f;
  switch(ti){
    case 0:  k1g<0,0,0>(act2,b0,u,bh,ssa,ssb); break;
    case 1:  k1g<1,1,0>(act2,b0,u,bh,ssa,ssb); break;
    case 2:  k1g<2,2,0>(act2,b0,u,bh,ssa,ssb); break;
    case 3:  k1g<3,3,0>(act2,b0,u,bh,ssa,ssb); break;
    case 4:  k1g<1,0,1>(act2,b0,u,bh,ssa,ssb); break;
    case 5:  k1g<1,1,1>(act2,b0,u,bh,ssa,ssb); break;
    case 6:  k1g<2,1,1>(act2,b0,u,bh,ssa,ssb); break;
    case 7:  k1g<2,2,1>(act2,b0,u,bh,ssa,ssb); break;
    case 8:  k1g<3,2,1>(act2,b0,u,bh,ssa,ssb); break;
    case 9:  k1g<3,3,1>(act2,b0,u,bh,ssa,ssb); break;
    case 10: k1g<1,1,2>(act2,b0,u,bh,ssa,ssb); break;
    case 11: k1g<2,0,2>(act2,b0,u,bh,ssa,ssb); break;
    case 12: k1g<2,1,2>(act2,b0,u,bh,ssa,ssb); break;
    case 13: k1g<2,2,2>(act2,b0,u,bh,ssa,ssb); break;
    case 14: k1g<3,1,2>(act2,b0,u,bh,ssa,ssb); break;
    case 15: k1g<3,2,2>(act2,b0,u,bh,ssa,ssb); break;
    case 16: k1g<3,3,2>(act2,b0,u,bh,ssa,ssb); break;
    case 17: k1g<2,1,3>(act2,b0,u,bh,ssa,ssb); break;
    case 18: k1g<2,2,3>(act2,b0,u,bh,ssa,ssb); break;
    case 19: k1g<3,0,3>(act2,b0,u,bh,ssa,ssb); break;
    case 20: k1g<3,1,3>(act2,b0,u,bh,ssa,ssb); break;
    case 21: k1g<3,2,3>(act2,b0,u,bh,ssa,ssb); break;
    default: k1g<3,3,3>(act2,b0,u,bh,ssa,ssb); break;
  }
  // coalesced partial store: row = ti*128 + chunk*2 + bh
  part[(size_t)((ti*64 + chunk)*2 + bh)*128 + u] = make_float2(ssa, ssb);
}

// ==== K2: tiny — reduce 128 partial rows per triple -> scale table s[5888] ====
__global__ __launch_bounds__(256) void k_scale(const float* __restrict__ bn,
                                               const float2* __restrict__ part,
                                               float* __restrict__ s){
  const int ti = blockIdx.x;                 // 23
  const int ch = threadIdx.x;                // 256 channels
  const int idx = ti*256 + ch;
  const int u = ch>>1;
  const float2* ps = part + (size_t)ti*128*128 + u;
  float sum = 0.f;
  #pragma unroll 8
  for(int r=0;r<128;++r){
    float2 v = ps[(size_t)r*128];
    sum += (ch&1) ? v.y : v.x;
  }
  int l = (idx<1024)?0 : (idx<2560)?1 : (idx<4352)?2 : 3;
  float divi = (l==0)?(1.f/2048.f) : (l==1)?(1.f/6144.f) : (l==2)?(1.f/10240.f) : (1.f/14336.f);
  float bstd = sqrtf(sum*divi);
  float nstd = 0.5f*(bn[idx]+bstd);
  s[idx] = 1.f/(nstd+1e-5f);
}

// ======== K3: fused recompute-GEMM (global-direct phase1, lean LDS) ========
// Block = 8 batches of one l. Per 64-word chunk:
//   { phase1 CG recompute (x s[ch]) -> btile, act read DIRECT from global
//     (block's 8 rows = 16 KB, L1/L2-hot);
//     land A chunk cc (loads issued LAST iteration -> latency hidden under
//     phase1's VALU) -> single ldsA buffer (safe: previous MFMA read ended
//     at the last barrier, which precedes this write in program order);
//     issue A loads for chunk cc+1; barrier;
//     MFMA (A from ldsA, B from btile); barrier }
// Full-K register accumulation -> single float2 store per output element.
// LDS = 17408 (btile) + 8704 (ldsA) = 26112 B.
// __launch_bounds__(256,3): natural VGPR (~84, NO spill — round-6 verified);
// at VGPR<=128 the HW schedules 4 waves/SIMD anyway (4 blocks/CU; LDS fits).
// (256,4) clamps to 64 VGPR and spills 27 MB of scratch — round-7 regression.

#define BT_B   0
#define LA_B   17408

template<int NTIL>
DEVFN void kf_pre(char* smem){
  const int tid = threadIdx.x;
  unsigned* btile = (unsigned*)(smem + BT_B);
  for(int i=tid; i<NTIL*16*BP; i+=256) btile[i]=0;
  __syncthreads();
}

template<int L1,int L2,int L,int Q,int NTIL>
DEVFN void kf_triple(const float2* __restrict__ act2, int b0, char* smem,
                     const unsigned* __restrict__ Aw,
                     const float* __restrict__ sg, f32x4& cR, f32x4& cI){
  constexpr int N1=2*L1+1, N2=2*L2+1, NP=2*L+1;
  constexpr int Ml = MLs(L);
  unsigned* btile  = (unsigned*)(smem + BT_B);
  unsigned* ldsA   = (unsigned*)(smem + LA_B);
  const int tid = threadIdx.x;
  const int lane = tid & 63, w = tid >> 6;
  const int col = lane & 15, quad = lane >> 4;
  const int up = tid & 31, bi = tid >> 5;    // channel-pair-in-chunk, batch
  const int r0 = tid>>4,       j0 = (tid&15)*4;
  const int r1 = (tid+256)>>4;
  const float2* arow = act2 + (size_t)(b0+bi)*256;
  // issue chunk-0 A loads (land after phase1 of cc=0)
  uint4 v0 = *(const uint4*)(Aw + (size_t)r0*Ml + Q*256 + j0);
  uint4 v1 = *(const uint4*)(Aw + (size_t)r1*Ml + Q*256 + j0);
  #pragma unroll 1
  for(int cc=0; cc<4; ++cc){
    // ---- phase1: CG recompute (scaled) for 64 K-words x 8 batches ----
    {
      const float2 s2 = *(const float2*)(sg + SOFF(L) + Q*256 + cc*64 + 2*up);
      const int u = cc*32 + up;              // channel pair (2u,2u+1)
      const int t = u>>3, s0 = (u&7)*2;
      float2 F1[N1], F2a[N2], F2b[N2], mida[NP], midb[NP];
      #pragma unroll
      for(int m=0;m<N1;++m) F1[m]=arow[AOFF(L1)+t*N1+m];
      #pragma unroll
      for(int n=0;n<N2;++n){
        F2a[n]=arow[AOFF(L2)+s0*N2+n];
        F2b[n]=arow[AOFF(L2)+(s0+1)*N2+n];
      }
      #pragma unroll
      for(int p=0;p<NP;++p){ mida[p]=make_float2(0.f,0.f); midb[p]=make_float2(0.f,0.f); }
      cg_accum<L1,L2,L>(F1,F2a,mida);
      cg_accum<L1,L2,L>(F1,F2b,midb);
      #pragma unroll
      for(int p=0;p<NP;++p){
        uint2 v;
        v.x = f2bf2(mida[p].x*s2.x, mida[p].y*s2.x);
        v.y = f2bf2(midb[p].x*s2.y, midb[p].y*s2.y);
        *(uint2*)(btile + (size_t)(bi*NP+p)*BP + 2*up) = v;
      }
    }
    // ---- land A chunk cc (loads issued last iteration / prologue) ----
    *(uint4*)(ldsA + r0*AP + j0) = v0;
    *(uint4*)(ldsA + r1*AP + j0) = v1;
    // ---- issue A loads for chunk cc+1 (hidden under next phase1) ----
    if(cc<3){
      const int base = Q*256 + (cc+1)*64;
      v0 = *(const uint4*)(Aw + (size_t)r0*Ml + base + j0);
      v1 = *(const uint4*)(Aw + (size_t)r1*Ml + base + j0);
    }
    __syncthreads();
    // ---- MFMA accumulate (A and B both from LDS) ----
    if(w < NTIL){
      const unsigned* ar0 = ldsA + col*AP + quad*4;
      const unsigned* ar1 = ldsA + (col+16)*AP + quad*4;
      const unsigned* bb  = btile + (w*16+col)*BP + quad*4;
      #pragma unroll
      for(int ks=0; ks<4; ++ks){
        bf16x8 b  = *(const bf16x8*)(bb + ks*16);
        bf16x8 A0 = *(const bf16x8*)(ar0 + ks*16);
        bf16x8 A1 = *(const bf16x8*)(ar1 + ks*16);
        cR = __builtin_amdgcn_mfma_f32_16x16x32_bf16(A0, b, cR, 0, 0, 0);
        cI = __builtin_amdgcn_mfma_f32_16x16x32_bf16(A1, b, cI, 0, 0, 0);
      }
    }
    __syncthreads();
  }
}

template<int L,int NTIL>
DEVFN void kf_epi(float* __restrict__ out, int b0, f32x4 cR, f32x4 cI){
  constexpr int NP = 2*L+1;
  const int tid = threadIdx.x, lane = tid & 63, w = tid >> 6;
  const int col = lane & 15, quad = lane >> 4;
  if(w < NTIL){
    const int r = w*16 + col;
    if(r < 8*NP){
      const int b = b0 + r/NP, p = r - (r/NP)*NP;
      float2* o2 = (float2*)out + (size_t)b*256 + AOFF(L);
      #pragma unroll
      for(int i=0;i<4;++i) o2[(quad*4+i)*NP + p] = make_float2(cR[i], cI[i]);
    }
  }
}

__global__ __launch_bounds__(256,3) void k_fusedall(const float* __restrict__ act,
    const short* __restrict__ A, const float* __restrict__ sg,
    float* __restrict__ out){
  __shared__ __align__(16) char smem[26112];
  const int bid = blockIdx.x;                             // 1024
  const float2* act2 = (const float2*)act;
  f32x4 cR={0.f,0.f,0.f,0.f}, cI={0.f,0.f,0.f,0.f};
  if(bid < 256){                                          // l=3, rows 56, NTIL 4
    const int b0 = bid*8;
    kf_pre<4>(smem);
    const unsigned* Aw=(const unsigned*)(A+ABASE(3));
    kf_triple<2,1,3,0,4>(act2,b0,smem,Aw,sg,cR,cI);
    kf_triple<2,2,3,1,4>(act2,b0,smem,Aw,sg,cR,cI);
    kf_triple<3,0,3,2,4>(act2,b0,smem,Aw,sg,cR,cI);
    kf_triple<3,1,3,3,4>(act2,b0,smem,Aw,sg,cR,cI);
    kf_triple<3,2,3,4,4>(act2,b0,smem,Aw,sg,cR,cI);
    kf_triple<3,3,3,5,4>(act2,b0,smem,Aw,sg,cR,cI);
    kf_epi<3,4>(out,b0,cR,cI);
  } else if(bid < 512){                                   // l=2, rows 40, NTIL 3
    const int b0 = (bid-256)*8;
    kf_pre<3>(smem);
    const unsigned* Aw=(const unsigned*)(A+ABASE(2));
    kf_triple<1,1,2,0,3>(act2,b0,smem,Aw,sg,cR,cI);
    kf_triple<2,0,2,1,3>(act2,b0,smem,Aw,sg,cR,cI);
    kf_triple<2,1,2,2,3>(act2,b0,smem,Aw,sg,cR,cI);
    kf_triple<2,2,2,3,3>(act2,b0,smem,Aw,sg,cR,cI);
    kf_triple<3,1,2,4,3>(act2,b0,smem,Aw,sg,cR,cI);
    kf_triple<3,2,2,5,3>(act2,b0,smem,Aw,sg,cR,cI);
    kf_triple<3,3,2,6,3>(act2,b0,smem,Aw,sg,cR,cI);
    kf_epi<2,3>(out,b0,cR,cI);
  } else if(bid < 768){                                   // l=1, rows 24, NTIL 2
    const int b0 = (bid-512)*8;
    kf_pre<2>(smem);
    const unsigned* Aw=(const unsigned*)(A+ABASE(1));
    kf_triple<1,0,1,0,2>(act2,b0,smem,Aw,sg,cR,cI);
    kf_triple<1,1,1,1,2>(act2,b0,smem,Aw,sg,cR,cI);
    kf_triple<2,1,1,2,2>(act2,b0,smem,Aw,sg,cR,cI);
    kf_triple<2,2,1,3,2>(act2,b0,smem,Aw,sg,cR,cI);
    kf_triple<3,2,1,4,2>(act2,b0,smem,Aw,sg,cR,cI);
    kf_triple<3,3,1,5,2>(act2,b0,smem,Aw,sg,cR,cI);
    kf_epi<1,2>(out,b0,cR,cI);
  } else {                                                // l=0, rows 8, NTIL 1
    const int b0 = (bid-768)*8;
    kf_pre<1>(smem);
    const unsigned* Aw=(const unsigned*)(A+ABASE(0));
    kf_triple<0,0,0,0,1>(act2,b0,smem,Aw,sg,cR,cI);
    kf_triple<1,1,0,1,1>(act2,b0,smem,Aw,sg,cR,cI);
    kf_triple<2,2,0,2,1>(act2,b0,smem,Aw,sg,cR,cI);
    kf_triple<3,3,0,3,1>(act2,b0,smem,Aw,sg,cR,cI);
    kf_epi<0,1>(out,b0,cR,cI);
  }
}

// ================= host launch =================
extern "C" void kernel_launch(void* const* d_in, const int* in_sizes, int n_in,
                              void* d_out, int out_size, void* d_ws, size_t ws_size,
                              hipStream_t stream) {
  const float* act = (const float*)d_in[0];   // (2048,256,2) f32
  const float* W   = (const float*)d_in[1];   // (94208,2) f32
  const float* bn  = (const float*)d_in[2];   // (5888,) f32
  float* out = (float*)d_out;                 // (2048,256,2) f32

  float*  s    = (float*)d_ws;                            // 5888 f32 scale table
  short*  A    = (short*)((char*)d_ws + 24576);           // 754 KB bf16 A (unscaled)
  float2* part = (float2*)((char*)d_ws + 1048576);        // 3 MB partials

  hipLaunchKernelGGL(k_sumsq,   dim3(1495), dim3(256), 0, stream, act, part, W, A);
  hipLaunchKernelGGL(k_scale,   dim3(23),   dim3(256), 0, stream, bn, part, s);
  hipLaunchKernelGGL(k_fusedall,dim3(1024), dim3(256), 0, stream, act, A, s, out);
}